// Round 4
// baseline (3094.915 us; speedup 1.0000x reference)
//
#include <hip/hip_runtime.h>
#include <hip/hip_bf16.h>

#define BB 64
#define NN 256
#define DD 512
#define EE 10

typedef __bf16 bf16x8 __attribute__((ext_vector_type(8)));
typedef unsigned short ushort8v __attribute__((ext_vector_type(8)));
typedef unsigned int uint4v __attribute__((ext_vector_type(4)));
typedef unsigned int uint2v __attribute__((ext_vector_type(2)));
typedef float floatx4 __attribute__((ext_vector_type(4)));
typedef float floatx16 __attribute__((ext_vector_type(16)));

typedef __attribute__((address_space(3))) unsigned short lds_us;
typedef const __attribute__((address_space(1))) unsigned short glb_us;

__device__ __forceinline__ unsigned short f2b(float f) {
    union { float f; unsigned u; } x; x.f = f;
    unsigned r = x.u + 0x7FFFu + ((x.u >> 16) & 1u);
    return (unsigned short)(r >> 16);
}
__device__ __forceinline__ float b2f(unsigned short u) {
    union { unsigned u; float f; } x; x.u = ((unsigned)u) << 16;
    return x.f;
}
// pack two rounded bf16 (hi=a, lo=b) from f32 bit patterns via byte-perm
__device__ __forceinline__ unsigned pack_bf16(float a, float b) {
    union { float f; unsigned u; } xa, xb2; xa.f = a; xb2.f = b;
    return __builtin_amdgcn_perm(xa.u + 0x8000u, xb2.u + 0x8000u, 0x07060302u);
}

// ---------------- K0a: W_edge/W_self -> Wf in 32x32x16 MFMA-B fragment order.
__global__ void k_wconv(const float* __restrict__ W_edge,
                        const float* __restrict__ W_self,
                        unsigned short* __restrict__ Wf) {
    int t = blockIdx.x * 256 + threadIdx.x;   // grid 1408 -> 360448 exact
    int lane  = t & 63;
    int kstep = (t >> 6) & 31;
    int cfg   = (t >> 11) & 15;
    int e     = t >> 15;                      // 0..10
    int dout = cfg * 32 + (lane & 31);
    int k    = kstep * 16 + (lane >> 5) * 8;
    const float* src = (e < EE) ? (W_edge + ((size_t)e * DD + dout) * DD + k)
                                : (W_self + (size_t)dout * DD + k);
    ushort8v o;
    #pragma unroll
    for (int j = 0; j < 8; j++) o[j] = f2b(src[j]);
    *(ushort8v*)(Wf + (size_t)t * 8) = o;
}

// ---------------- K0b: pack graph bits + recip(neigh). One block per (b,n).
__global__ void k_graph(const int* __restrict__ adj, const int* __restrict__ mask,
                        unsigned* __restrict__ packed, float* __restrict__ recip) {
    int b = blockIdx.x >> 8;
    int n = blockIdx.x & 255;
    int lane = threadIdx.x & 63;
    int wv   = threadIdx.x >> 6;   // 0..3
    int m = wv * 64 + lane;
    int ok = (mask[b * NN + n] != 0) & (mask[b * NN + m] != 0) & (m != n);
    __shared__ int cnt_s[4];
    int total = 0;
    #pragma unroll
    for (int e = 0; e < EE; e++) {
        int a = adj[(((size_t)e * BB + b) * NN + n) * NN + m];
        int bit = ok & (a != 0);
        unsigned long long bal = __ballot(bit);
        if (lane == 0) {
            unsigned* dst = packed + (((size_t)e * BB + b) * NN + n) * 8 + wv * 2;
            dst[0] = (unsigned)bal;
            dst[1] = (unsigned)(bal >> 32);
        }
        total += bit;
    }
    for (int off = 32; off; off >>= 1) total += __shfl_down(total, off);
    if (lane == 0) cnt_s[wv] = total;
    __syncthreads();
    if (threadIdx.x == 0) {
        int c = cnt_s[0] + cnt_s[1] + cnt_s[2] + cnt_s[3];
        recip[b * NN + n] = 1.0f / (float)(c < 1 ? 1 : c);
    }
}

// ---------------- K1 fused: gate + bf16 copy + frag-order wTf build.
// Grid 1024 = (b, ms): block handles 16 rows (n = ms*16..+16) x 512 d.
template<int TI>
__global__ __launch_bounds__(256)
void k_gt(const float* __restrict__ xf, const unsigned short* __restrict__ xbin,
          const float* __restrict__ W_nw, const float* __restrict__ b_nw,
          float* __restrict__ w_out, unsigned short* __restrict__ wTf,
          unsigned short* __restrict__ xb0) {
    int bid = blockIdx.x;
    int b  = bid >> 4;
    int ms = bid & 15;
    __shared__ float part[16][17];
    __shared__ float wsig[16];
    int t = threadIdx.x;
    int row = t >> 4;          // 0..15 local n
    int seg = t & 15;          // 32-d segment
    size_t g = ((size_t)(b * NN + ms * 16 + row)) * DD + seg * 32;
    float s = 0.f;
    if (TI == 0) {
        const floatx4* xp = (const floatx4*)(xf + g);
        const floatx4* wp = (const floatx4*)(W_nw + seg * 32);
        #pragma unroll
        for (int k = 0; k < 4; k++) {
            floatx4 a = xp[2 * k], c4 = xp[2 * k + 1];
            floatx4 wa = wp[2 * k], wc = wp[2 * k + 1];
            ushort8v u;
            #pragma unroll
            for (int j = 0; j < 4; j++) {
                s += a[j] * wa[j] + c4[j] * wc[j];
                u[j] = f2b(a[j]); u[4 + j] = f2b(c4[j]);
            }
            *(ushort8v*)(xb0 + g + k * 8) = u;
        }
    } else {
        const ushort8v* xp = (const ushort8v*)(xbin + g);
        const float* wp = W_nw + seg * 32;
        #pragma unroll
        for (int k = 0; k < 4; k++) {
            ushort8v u = xp[k];
            #pragma unroll
            for (int j = 0; j < 8; j++) s += b2f(u[j]) * wp[k * 8 + j];
        }
    }
    part[row][seg] = s;
    __syncthreads();
    if (t < 16) {
        float tot = 0.f;
        #pragma unroll
        for (int i = 0; i < 16; i++) tot += part[t][i];
        float v = 1.f / (1.f + __expf(-(tot + b_nw[0])));
        wsig[t] = v;
        w_out[(b * 2 + TI) * NN + ms * 16 + t] = v;
    }
    __syncthreads();
    // phase 2: write wTf frag-order (elem j = x[m=ms*16+hi*8+j][dd*32+l31] * w[m])
    #pragma unroll
    for (int c = 0; c < 4; c++) {
        int slot = t + 256 * c;          // 0..1023
        int dd_  = slot >> 6;            // 0..15
        int lane = slot & 63;
        int l31 = lane & 31, hi = lane >> 5;
        size_t xrow = ((size_t)(b * NN + ms * 16 + hi * 8)) * DD + dd_ * 32 + l31;
        ushort8v o;
        #pragma unroll
        for (int j = 0; j < 8; j++) {
            float xv = (TI == 0) ? xf[xrow + (size_t)j * DD] : b2f(xbin[xrow + (size_t)j * DD]);
            o[j] = f2b(xv * wsig[hi * 8 + j]);
        }
        *(ushort8v*)(wTf + ((((size_t)b * 16 + ms) * 16 + dd_) * 64 + lane) * 8) = o;
    }
}

// ---------------- K2 v5: v4's replay-proven chassis (explicit asm drains,
// e-outer/dc-inner, per-step sWT staging, sTf dbuf, ct-split grid 512 =
// 2 blocks/CU) + balanced producer/consumer wave split:
//   * waves 0-3 (producers): stage-1 only. Single-chain 16 MFMA. Bg[16]
//     cached, refreshed once per e (every 8 steps) -- kills v4's 60% VALUBusy.
//   * waves 4-7 (consumers): stage-2 only. 16 MFMA (acc2[2][2], 64 dout/wave).
//     Wf B-frags hoisted to regs right after the barrier (L2 latency hides
//     under sTf ds_reads).
// VGPR: producer ~105 (Bg 64 + acc3 16), consumer ~110 (acc2 64 + bfr 32);
// both <=128 so __launch_bounds__(512,4) holds without spills.
template<int TI>
__global__ __launch_bounds__(512, 4)
void k2_heavy(const unsigned short* __restrict__ wTf,   // [b][ms16][dd16][lane][8] frag order
              const unsigned short* __restrict__ xb,    // [B][N][D] bf16 (self A)
              const unsigned short* __restrict__ Wf,    // 32x32 frag order [11][cf16][ks32][lane][8]
              const unsigned* __restrict__ packed,      // [E][B][N][8]
              const float* __restrict__ recip,          // [B][N]
              const float* __restrict__ b_self,         // [D]
              unsigned short* __restrict__ out_bf16,    // t=0
              float* __restrict__ out_f32) {            // t=1
    __shared__ __attribute__((aligned(16))) unsigned short sWT[2][32 * 512]; // 64 KB dbuf
    __shared__ __attribute__((aligned(16))) unsigned short sTf[2][8 * 512];  // 16 KB dbuf

    int bid = blockIdx.x;
    int b  = bid & 63;                 // same-b siblings share XCD (bid%8 == b%8)
    int nq = (bid >> 6) & 3;           // 64-row n quarter
    int ct = bid >> 8;                 // 256-dout half
    int w = threadIdx.x >> 6, lane = threadIdx.x & 63;
    int l31 = lane & 31, hi = lane >> 5;

    // producer role (w<4): sd = 32-d half of 64-d chunk, sn = 32-n half
    int sd = w & 1, sn = (w >> 1) & 1;
    int gn1 = nq * 64 + sn * 32 + l31;            // global n (stage-1 C col)
    float rn = recip[b * NN + gn1];
    // consumer role (w>=4): wc = 64-dout slice within ct-half
    int wc = w & 3;

    floatx16 acc2[2][2];                          // [nb][cb] (consumers only)
    #pragma unroll
    for (int i = 0; i < 2; i++)
        #pragma unroll
        for (int jj = 0; jj < 2; jj++)
            #pragma unroll
            for (int q = 0; q < 16; q++) acc2[i][jj][q] = 0.f;

    auto stage_sWT = [&](int dcs, int buf) {      // all 8 waves, 4 instrs each
        #pragma unroll
        for (int it = 0; it < 4; it++) {
            int c = it * 8 + w;                   // 0..31: ms = c>>1, dbl = c&1
            const unsigned short* g = wTf +
                ((((size_t)b * 16 + (c >> 1)) * 16 + dcs * 2 + (c & 1)) * 64 + lane) * 8;
            __builtin_amdgcn_global_load_lds((glb_us*)g, (lds_us*)&sWT[buf][c * 512], 16, 0, 0);
        }
    };

    // prime step 0
    stage_sWT(0, 0);

    const unsigned short* WfL = Wf + lane * 8;
    const unsigned short* xbL = xb + ((size_t)(b * NN + nq * 64 + l31)) * DD + hi * 8;

    bf16x8 Bg[16];     // producer stage-1 B (expanded graph bits), per-e cache

    // steps: s in [0,89). stage1 produces chunk s (s<80, e=s>>3, dc=s&7) into
    // sTf[s&1]; stage2 consumes chunk s-1 (edge for q<80, self for q>=80).
    #pragma unroll 1
    for (int s = 0; s < 89; s++) {
        int cur = s & 1;
        if (s <= 80) {
            asm volatile("s_waitcnt vmcnt(0) lgkmcnt(0)" ::: "memory");
            __builtin_amdgcn_s_barrier();
            if (s + 1 < 80) stage_sWT((s + 1) & 7, (s + 1) & 1);
        }
        // ---------- stage 1 (producers): T chunk s = (masked_w @ x), 64d x 64n --
        if (s < 80 && w < 4) {
            int e = s >> 3;
            if ((s & 7) == 0) {
                // refresh Bg once per e (round-0 proven expansion)
                const uint4v* pp = (const uint4v*)(packed +
                    (((size_t)e * BB + b) * NN + gn1) * 8);
                uint4v pa = pp[0], pbv = pp[1];
                unsigned pw[8] = {pa[0], pa[1], pa[2], pa[3], pbv[0], pbv[1], pbv[2], pbv[3]};
                #pragma unroll
                for (int ks = 0; ks < 16; ks++) {
                    int byi = ks * 2 + hi;
                    unsigned byte_ = (pw[byi >> 2] >> ((byi & 3) * 8)) & 0xFFu;
                    uint4v av;
                    #pragma unroll
                    for (int p2 = 0; p2 < 4; p2++) {
                        unsigned tt = (byte_ >> (2 * p2)) & 3u;
                        av[p2] = ((tt | (tt << 15)) & 0x10001u) * 0x3F80u;
                    }
                    Bg[ks] = __builtin_bit_cast(bf16x8, av);
                }
            }
            floatx16 acc3;
            #pragma unroll
            for (int q = 0; q < 16; q++) acc3[q] = 0.f;
            #pragma unroll
            for (int ks = 0; ks < 16; ks++) {
                bf16x8 afr = __builtin_bit_cast(bf16x8,
                    *(const ushort8v*)&sWT[cur][(ks * 2 + sd) * 512 + lane * 8]);
                acc3 = __builtin_amdgcn_mfma_f32_32x32x16_bf16(afr, Bg[ks], acc3, 0, 0, 0);
            }
            // scale by recip(n), pack, write frag-order sTf[cur]
            #pragma unroll
            for (int g = 0; g < 4; g++) {
                float v0 = acc3[g * 4 + 0] * rn;
                float v1 = acc3[g * 4 + 1] * rn;
                float v2 = acc3[g * 4 + 2] * rn;
                float v3 = acc3[g * 4 + 3] * rn;
                uint2v pk;
                pk[0] = pack_bf16(v1, v0);
                pk[1] = pack_bf16(v3, v2);
                int kk = sd * 2 + (g >> 1);
                int slot = (kk * 2 + sn) * 64 + (g & 1) * 32 + l31;
                *(uint2v*)&sTf[cur][slot * 8 + 4 * hi] = pk;
            }
        }
        // ---------- stage 2 (consumers): acc2 += chunk(s-1) @ W column ----------
        if (s >= 1 && w >= 4) {
            int q = s - 1;
            int qe = q >> 3, qdc = q & 7, pb2 = q & 1;
            if (qe < EE) {
                // hoist the 8 Wf B-frags first: global loads issue early,
                // latency hides under the sTf ds_reads below
                bf16x8 bfr[4][2];
                #pragma unroll
                for (int kk = 0; kk < 4; kk++)
                    #pragma unroll
                    for (int cb = 0; cb < 2; cb++)
                        bfr[kk][cb] = __builtin_bit_cast(bf16x8, *(const ushort8v*)
                            &WfL[(size_t)(((qe * 16 + ct * 8 + wc * 2 + cb) * 32 + qdc * 4 + kk)) * 512]);
                const unsigned short* sTfL = &sTf[pb2][lane * 8];
                #pragma unroll
                for (int kk = 0; kk < 4; kk++) {
                    bf16x8 afr0 = __builtin_bit_cast(bf16x8,
                        *(const ushort8v*)&sTfL[(kk * 2 + 0) * 512]);
                    bf16x8 afr1 = __builtin_bit_cast(bf16x8,
                        *(const ushort8v*)&sTfL[(kk * 2 + 1) * 512]);
                    #pragma unroll
                    for (int cb = 0; cb < 2; cb++) {
                        acc2[0][cb] = __builtin_amdgcn_mfma_f32_32x32x16_bf16(
                            afr0, bfr[kk][cb], acc2[0][cb], 0, 0, 0);
                        acc2[1][cb] = __builtin_amdgcn_mfma_f32_32x32x16_bf16(
                            afr1, bfr[kk][cb], acc2[1][cb], 0, 0, 0);
                    }
                }
            } else {
                // self path: A direct from xb, barrier-free tail (steps 81..88)
                bf16x8 bfr[4][2];
                #pragma unroll
                for (int kk = 0; kk < 4; kk++)
                    #pragma unroll
                    for (int cb = 0; cb < 2; cb++)
                        bfr[kk][cb] = __builtin_bit_cast(bf16x8, *(const ushort8v*)
                            &WfL[(size_t)(((EE * 16 + ct * 8 + wc * 2 + cb) * 32 + qdc * 4 + kk)) * 512]);
                #pragma unroll
                for (int kk = 0; kk < 4; kk++) {
                    bf16x8 afr0 = __builtin_bit_cast(bf16x8, *(const ushort8v*)
                        &xbL[(size_t)0 * 32 * DD + qdc * 64 + kk * 16]);
                    bf16x8 afr1 = __builtin_bit_cast(bf16x8, *(const ushort8v*)
                        &xbL[(size_t)1 * 32 * DD + qdc * 64 + kk * 16]);
                    #pragma unroll
                    for (int cb = 0; cb < 2; cb++) {
                        acc2[0][cb] = __builtin_amdgcn_mfma_f32_32x32x16_bf16(
                            afr0, bfr[kk][cb], acc2[0][cb], 0, 0, 0);
                        acc2[1][cb] = __builtin_amdgcn_mfma_f32_32x32x16_bf16(
                            afr1, bfr[kk][cb], acc2[1][cb], 0, 0, 0);
                    }
                }
            }
        }
    }
    // ---- epilogue (consumers): +b_self, relu, store (C rows=n, cols=dout) ----
    if (w >= 4) {
        #pragma unroll
        for (int cb = 0; cb < 2; cb++) {
            int col = ct * 256 + wc * 64 + cb * 32 + l31;
            float bs = b_self[col];
            #pragma unroll
            for (int nb = 0; nb < 2; nb++) {
                #pragma unroll
                for (int rg = 0; rg < 16; rg++) {
                    int row = nq * 64 + nb * 32 + (rg & 3) + 8 * (rg >> 2) + 4 * hi;
                    float v = acc2[nb][cb][rg] + bs;
                    v = v > 0.f ? v : 0.f;
                    size_t gi = ((size_t)b * NN + row) * DD + col;
                    if (TI == 0) out_bf16[gi] = f2b(v);
                    else         out_f32[gi] = v;
                }
            }
        }
    }
}

extern "C" void kernel_launch(void* const* d_in, const int* in_sizes, int n_in,
                              void* d_out, int out_size, void* d_ws, size_t ws_size,
                              hipStream_t stream) {
    const float* node   = (const float*)d_in[0];
    const float* W_nw   = (const float*)d_in[1];
    const float* b_nw   = (const float*)d_in[2];
    const float* W_self = (const float*)d_in[3];
    const float* b_self = (const float*)d_in[4];
    const float* W_edge = (const float*)d_in[5];
    const int*   mask   = (const int*)d_in[6];
    const int*   adj    = (const int*)d_in[7];
    float* out = (float*)d_out;
    float* out_w = out + (size_t)BB * NN * DD;   // all_weight region [B][2][N]

    char* ws = (char*)d_ws;
    size_t off = 0;
    unsigned short* Wf    = (unsigned short*)(ws + off); off += (size_t)11 * DD * DD * 2;      // 5.77 MB
    unsigned short* wTf   = (unsigned short*)(ws + off); off += (size_t)BB * DD * NN * 2;      // 16.78 MB
    unsigned short* xb0   = (unsigned short*)(ws + off); off += (size_t)BB * NN * DD * 2;      // 16.78 MB
    unsigned short* xb1   = (unsigned short*)(ws + off); off += (size_t)BB * NN * DD * 2;      // 16.78 MB
    unsigned*       packed= (unsigned*)(ws + off);       off += (size_t)EE * BB * NN * 8 * 4;  // 5.24 MB
    float*          recip = (float*)(ws + off);          off += (size_t)BB * NN * 4;

    k_wconv<<<dim3(1408), dim3(256), 0, stream>>>(W_edge, W_self, Wf);
    k_graph<<<dim3(16384), dim3(256), 0, stream>>>(adj, mask, packed, recip);

    // iteration 0
    k_gt<0><<<dim3(1024), dim3(256), 0, stream>>>(node, nullptr, W_nw, b_nw, out_w, wTf, xb0);
    k2_heavy<0><<<dim3(512), dim3(512), 0, stream>>>(wTf, xb0, Wf, packed, recip, b_self, xb1, nullptr);

    // iteration 1
    k_gt<1><<<dim3(1024), dim3(256), 0, stream>>>(nullptr, xb1, W_nw, b_nw, out_w, wTf, nullptr);
    k2_heavy<1><<<dim3(512), dim3(512), 0, stream>>>(wTf, xb1, Wf, packed, recip, b_self, nullptr, out);
}

// Round 6
// 769.913 us; speedup vs baseline: 4.0198x; 4.0198x over previous
//
#include <hip/hip_runtime.h>
#include <hip/hip_bf16.h>

#define BB 64
#define NN 256
#define DD 512
#define EE 10

typedef __bf16 bf16x8 __attribute__((ext_vector_type(8)));
typedef unsigned short ushort8v __attribute__((ext_vector_type(8)));
typedef unsigned int uint4v __attribute__((ext_vector_type(4)));
typedef unsigned int uint2v __attribute__((ext_vector_type(2)));
typedef float floatx4 __attribute__((ext_vector_type(4)));
typedef float floatx16 __attribute__((ext_vector_type(16)));

typedef __attribute__((address_space(3))) unsigned short lds_us;
typedef const __attribute__((address_space(1))) unsigned short glb_us;

__device__ __forceinline__ unsigned short f2b(float f) {
    union { float f; unsigned u; } x; x.f = f;
    unsigned r = x.u + 0x7FFFu + ((x.u >> 16) & 1u);
    return (unsigned short)(r >> 16);
}
__device__ __forceinline__ float b2f(unsigned short u) {
    union { unsigned u; float f; } x; x.u = ((unsigned)u) << 16;
    return x.f;
}
// pack two rounded bf16 (hi=a, lo=b) from f32 bit patterns via byte-perm
__device__ __forceinline__ unsigned pack_bf16(float a, float b) {
    union { float f; unsigned u; } xa, xb2; xa.f = a; xb2.f = b;
    return __builtin_amdgcn_perm(xa.u + 0x8000u, xb2.u + 0x8000u, 0x07060302u);
}
// proven expansion: byte bits -> 8 bf16 {0,1}; elem j = bit j
__device__ __forceinline__ bf16x8 expand_byte(unsigned byte_) {
    uint4v av;
    #pragma unroll
    for (int p2 = 0; p2 < 4; p2++) {
        unsigned tt = (byte_ >> (2 * p2)) & 3u;
        av[p2] = ((tt | (tt << 15)) & 0x10001u) * 0x3F80u;
    }
    return __builtin_bit_cast(bf16x8, av);
}

// ---------------- K0a: W_edge/W_self -> Wf in 32x32x16 MFMA-B fragment order.
__global__ void k_wconv(const float* __restrict__ W_edge,
                        const float* __restrict__ W_self,
                        unsigned short* __restrict__ Wf) {
    int t = blockIdx.x * 256 + threadIdx.x;   // grid 1408 -> 360448 exact
    int lane  = t & 63;
    int kstep = (t >> 6) & 31;
    int cfg   = (t >> 11) & 15;
    int e     = t >> 15;                      // 0..10
    int dout = cfg * 32 + (lane & 31);
    int k    = kstep * 16 + (lane >> 5) * 8;
    const float* src = (e < EE) ? (W_edge + ((size_t)e * DD + dout) * DD + k)
                                : (W_self + (size_t)dout * DD + k);
    ushort8v o;
    #pragma unroll
    for (int j = 0; j < 8; j++) o[j] = f2b(src[j]);
    *(ushort8v*)(Wf + (size_t)t * 8) = o;
}

// ---------------- K0b: pack graph bits + recip(neigh). One block per (b,n).
__global__ void k_graph(const int* __restrict__ adj, const int* __restrict__ mask,
                        unsigned* __restrict__ packed, float* __restrict__ recip) {
    int b = blockIdx.x >> 8;
    int n = blockIdx.x & 255;
    int lane = threadIdx.x & 63;
    int wv   = threadIdx.x >> 6;   // 0..3
    int m = wv * 64 + lane;
    int ok = (mask[b * NN + n] != 0) & (mask[b * NN + m] != 0) & (m != n);
    __shared__ int cnt_s[4];
    int total = 0;
    #pragma unroll
    for (int e = 0; e < EE; e++) {
        int a = adj[(((size_t)e * BB + b) * NN + n) * NN + m];
        int bit = ok & (a != 0);
        unsigned long long bal = __ballot(bit);
        if (lane == 0) {
            unsigned* dst = packed + (((size_t)e * BB + b) * NN + n) * 8 + wv * 2;
            dst[0] = (unsigned)bal;
            dst[1] = (unsigned)(bal >> 32);
        }
        total += bit;
    }
    for (int off = 32; off; off >>= 1) total += __shfl_down(total, off);
    if (lane == 0) cnt_s[wv] = total;
    __syncthreads();
    if (threadIdx.x == 0) {
        int c = cnt_s[0] + cnt_s[1] + cnt_s[2] + cnt_s[3];
        recip[b * NN + n] = 1.0f / (float)(c < 1 ? 1 : c);
    }
}

// ---------------- K1 fused: gate + bf16 copy + frag-order wTf build.
// Grid 1024 = (b, ms): block handles 16 rows (n = ms*16..+16) x 512 d.
template<int TI>
__global__ __launch_bounds__(256)
void k_gt(const float* __restrict__ xf, const unsigned short* __restrict__ xbin,
          const float* __restrict__ W_nw, const float* __restrict__ b_nw,
          float* __restrict__ w_out, unsigned short* __restrict__ wTf,
          unsigned short* __restrict__ xb0) {
    int bid = blockIdx.x;
    int b  = bid >> 4;
    int ms = bid & 15;
    __shared__ float part[16][17];
    __shared__ float wsig[16];
    int t = threadIdx.x;
    int row = t >> 4;          // 0..15 local n
    int seg = t & 15;          // 32-d segment
    size_t g = ((size_t)(b * NN + ms * 16 + row)) * DD + seg * 32;
    float s = 0.f;
    if (TI == 0) {
        const floatx4* xp = (const floatx4*)(xf + g);
        const floatx4* wp = (const floatx4*)(W_nw + seg * 32);
        #pragma unroll
        for (int k = 0; k < 4; k++) {
            floatx4 a = xp[2 * k], c4 = xp[2 * k + 1];
            floatx4 wa = wp[2 * k], wc = wp[2 * k + 1];
            ushort8v u;
            #pragma unroll
            for (int j = 0; j < 4; j++) {
                s += a[j] * wa[j] + c4[j] * wc[j];
                u[j] = f2b(a[j]); u[4 + j] = f2b(c4[j]);
            }
            *(ushort8v*)(xb0 + g + k * 8) = u;
        }
    } else {
        const ushort8v* xp = (const ushort8v*)(xbin + g);
        const float* wp = W_nw + seg * 32;
        #pragma unroll
        for (int k = 0; k < 4; k++) {
            ushort8v u = xp[k];
            #pragma unroll
            for (int j = 0; j < 8; j++) s += b2f(u[j]) * wp[k * 8 + j];
        }
    }
    part[row][seg] = s;
    __syncthreads();
    if (t < 16) {
        float tot = 0.f;
        #pragma unroll
        for (int i = 0; i < 16; i++) tot += part[t][i];
        float v = 1.f / (1.f + __expf(-(tot + b_nw[0])));
        wsig[t] = v;
        w_out[(b * 2 + TI) * NN + ms * 16 + t] = v;
    }
    __syncthreads();
    // phase 2: write wTf frag-order (elem j = x[m=ms*16+hi*8+j][dd*32+l31] * w[m])
    #pragma unroll
    for (int c = 0; c < 4; c++) {
        int slot = t + 256 * c;          // 0..1023
        int dd_  = slot >> 6;            // 0..15
        int lane = slot & 63;
        int l31 = lane & 31, hi = lane >> 5;
        size_t xrow = ((size_t)(b * NN + ms * 16 + hi * 8)) * DD + dd_ * 32 + l31;
        ushort8v o;
        #pragma unroll
        for (int j = 0; j < 8; j++) {
            float xv = (TI == 0) ? xf[xrow + (size_t)j * DD] : b2f(xbin[xrow + (size_t)j * DD]);
            o[j] = f2b(xv * wsig[hi * 8 + j]);
        }
        *(ushort8v*)(wTf + ((((size_t)b * 16 + ms) * 16 + dd_) * 64 + lane) * 8) = o;
    }
}

// ---------------- K2 v7: round-0's proven 2-barrier all-waves chassis,
// re-parameterized for 2 blocks/CU:
//   * tile 64n x 256dout, grid 512 (ct2 x b64 x nq4) -> 2 blocks/CU.
//   * step = 128-d chunk: 40 edge steps (e10 x dc2:4) + 4 barrier-free self.
//     Per step (every wave): stage-1 16 MFMA (dual chains, K=256, role =
//     32d(w>>1) x 32n(w&1)) + stage-2 16 MFMA (role = 32-dout col w).
//     Barriers/block halved vs r0 (88 -> ~80+prologue over 2x the blocks).
//   * LDS 80KB: sWT 64KB single-buf (staged at mid-step, r0 slot),
//     sTf 16KB single-buf (r0's mid-barrier handoff). -> 2x80 = 160KB/CU.
//   * Wf read direct from global in stage-2 (proven v2/v4/v5; L2-resident).
//   * graph bits: pw[8] regs cached per-e + proven tt|(tt<<15) expansion
//     per step (~224 VALU spread over ALL 8 waves). No register aliasing.
template<int TI>
__global__ __launch_bounds__(512, 4)
void k2_heavy(const unsigned short* __restrict__ wTf,   // [b][ms16][dd16][lane][8] frag order
              const unsigned short* __restrict__ xb,    // [B][N][D] bf16 (self A)
              const unsigned short* __restrict__ Wf,    // 32x32 frag order [11][cf16][ks32][lane][8]
              const unsigned* __restrict__ packed,      // [E][B][N][8]
              const float* __restrict__ recip,          // [B][N]
              const float* __restrict__ b_self,         // [D]
              unsigned short* __restrict__ out_bf16,    // t=0
              float* __restrict__ out_f32) {            // t=1
    __shared__ __attribute__((aligned(16))) unsigned short sWT[64 * 512]; // 64 KB
    __shared__ __attribute__((aligned(16))) unsigned short sTf[16 * 512]; // 16 KB

    int bid = blockIdx.x;
    int ct = bid & 1;                  // 256-dout half
    int b  = (bid >> 1) & 63;
    int nq = bid >> 7;                 // 64-row n quarter
    int w = threadIdx.x >> 6, lane = threadIdx.x & 63;
    int l31 = lane & 31, hi = lane >> 5;

    // stage-1 role (all waves): s1_d = 32d chunk of 128, s1_nb = 32n half
    int s1_d = w >> 1, s1_nb = w & 1;
    int gn1 = nq * 64 + s1_nb * 32 + l31;         // global n (stage-1 C col)
    float rn = recip[b * NN + gn1];
    // stage-2 role (all waves): w = 32-dout column within ct-half

    floatx16 acc2[2];                             // [nb 32n-half]
    #pragma unroll
    for (int i = 0; i < 2; i++)
        #pragma unroll
        for (int q = 0; q < 16; q++) acc2[i][q] = 0.f;

    auto stage_sWT = [&](int dc2) {               // 64 chunks, 8 per wave
        #pragma unroll
        for (int it = 0; it < 8; it++) {
            int c = it * 8 + w;                   // 0..63: ms = c>>2, dl = c&3
            const unsigned short* g = wTf +
                ((((size_t)b * 16 + (c >> 2)) * 16 + dc2 * 4 + (c & 3)) * 64 + lane) * 8;
            __builtin_amdgcn_global_load_lds((glb_us*)g, (lds_us*)&sWT[c * 512], 16, 0, 0);
        }
    };

    stage_sWT(0);   // prime step 0

    const unsigned short* WfL = Wf + lane * 8;
    const unsigned short* xbL = xb + ((size_t)(b * NN + nq * 64 + l31)) * DD + hi * 8;

    unsigned pw[8];   // packed graph row bits for n = gn1, current e

    #pragma unroll 1
    for (int s = 0; s < 40; s++) {
        int e = s >> 2, dc2 = s & 3;
        // ---- top sync: sWT chunk for this step has landed ----
        asm volatile("s_waitcnt vmcnt(0) lgkmcnt(0)" ::: "memory");
        __builtin_amdgcn_s_barrier();
        if ((s & 3) == 0) {
            const uint4v* pp = (const uint4v*)(packed +
                (((size_t)e * BB + b) * NN + gn1) * 8);
            uint4v pa = pp[0], pbv = pp[1];
            pw[0] = pa[0]; pw[1] = pa[1]; pw[2] = pa[2]; pw[3] = pa[3];
            pw[4] = pbv[0]; pw[5] = pbv[1]; pw[6] = pbv[2]; pw[7] = pbv[3];
        }
        // ---- stage 1 (all waves): 32d x 32n frag of T^T (128d x 64n), K=256 --
        {
            floatx16 acc3a, acc3b;   // dual chains over even/odd m-chunks
            #pragma unroll
            for (int q = 0; q < 16; q++) { acc3a[q] = 0.f; acc3b[q] = 0.f; }
            #pragma unroll
            for (int ks = 0; ks < 8; ks++) {
                // m-chunks 2ks and 2ks+1; bytes of pw[ks]: {hi, 2+hi}
                bf16x8 afrA = __builtin_bit_cast(bf16x8,
                    *(const ushort8v*)&sWT[((2 * ks) * 4 + s1_d) * 512 + lane * 8]);
                bf16x8 afrB = __builtin_bit_cast(bf16x8,
                    *(const ushort8v*)&sWT[((2 * ks + 1) * 4 + s1_d) * 512 + lane * 8]);
                unsigned wrd = pw[ks];
                bf16x8 bgA = expand_byte((wrd >> (hi * 8)) & 0xFFu);
                bf16x8 bgB = expand_byte((wrd >> ((2 + hi) * 8)) & 0xFFu);
                acc3a = __builtin_amdgcn_mfma_f32_32x32x16_bf16(afrA, bgA, acc3a, 0, 0, 0);
                acc3b = __builtin_amdgcn_mfma_f32_32x32x16_bf16(afrB, bgB, acc3b, 0, 0, 0);
            }
            // merge, scale by recip(n), pack, write frag-order sTf
            #pragma unroll
            for (int g = 0; g < 4; g++) {
                float v0 = (acc3a[g * 4 + 0] + acc3b[g * 4 + 0]) * rn;
                float v1 = (acc3a[g * 4 + 1] + acc3b[g * 4 + 1]) * rn;
                float v2 = (acc3a[g * 4 + 2] + acc3b[g * 4 + 2]) * rn;
                float v3 = (acc3a[g * 4 + 3] + acc3b[g * 4 + 3]) * rn;
                uint2v pk;
                pk[0] = pack_bf16(v1, v0);
                pk[1] = pack_bf16(v3, v2);
                int kk_w = s1_d * 2 + (g >> 1);           // 16-d chunk of 128
                int slot = (kk_w * 2 + s1_nb) * 64 + (g & 1) * 32 + l31;
                *(uint2v*)&sTf[slot * 8 + 4 * hi] = pk;
            }
        }
        // ---- mid sync: sTf visible; sWT dead ----
        asm volatile("s_waitcnt lgkmcnt(0)" ::: "memory");
        __builtin_amdgcn_s_barrier();
        if (s + 1 < 40) stage_sWT((s + 1) & 3);
        // ---- stage 2 (all waves): acc2 += T(64n x 128d) @ Wf col (32 dout) --
        #pragma unroll
        for (int kk = 0; kk < 8; kk++) {
            bf16x8 bfr = __builtin_bit_cast(bf16x8, *(const ushort8v*)
                &WfL[(size_t)(((e * 16 + ct * 8 + w) * 32 + dc2 * 8 + kk)) * 512]);
            bf16x8 afr0 = __builtin_bit_cast(bf16x8,
                *(const ushort8v*)&sTf[((kk * 2 + 0) * 64 + lane) * 8]);
            bf16x8 afr1 = __builtin_bit_cast(bf16x8,
                *(const ushort8v*)&sTf[((kk * 2 + 1) * 64 + lane) * 8]);
            acc2[0] = __builtin_amdgcn_mfma_f32_32x32x16_bf16(afr0, bfr, acc2[0], 0, 0, 0);
            acc2[1] = __builtin_amdgcn_mfma_f32_32x32x16_bf16(afr1, bfr, acc2[1], 0, 0, 0);
        }
    }
    // ---- self path: A direct from xb, barrier-free tail ----
    #pragma unroll 1
    for (int dc2 = 0; dc2 < 4; dc2++) {
        #pragma unroll
        for (int kk = 0; kk < 8; kk++) {
            bf16x8 bfr = __builtin_bit_cast(bf16x8, *(const ushort8v*)
                &WfL[(size_t)(((EE * 16 + ct * 8 + w) * 32 + dc2 * 8 + kk)) * 512]);
            bf16x8 afr0 = __builtin_bit_cast(bf16x8, *(const ushort8v*)
                &xbL[(size_t)0 * 32 * DD + (dc2 * 8 + kk) * 16]);
            bf16x8 afr1 = __builtin_bit_cast(bf16x8, *(const ushort8v*)
                &xbL[(size_t)1 * 32 * DD + (dc2 * 8 + kk) * 16]);
            acc2[0] = __builtin_amdgcn_mfma_f32_32x32x16_bf16(afr0, bfr, acc2[0], 0, 0, 0);
            acc2[1] = __builtin_amdgcn_mfma_f32_32x32x16_bf16(afr1, bfr, acc2[1], 0, 0, 0);
        }
    }
    // ---- epilogue: +b_self, relu, store (C rows=n, cols=dout) ----
    {
        int col = ct * 256 + w * 32 + l31;
        float bs = b_self[col];
        #pragma unroll
        for (int nb = 0; nb < 2; nb++) {
            #pragma unroll
            for (int rg = 0; rg < 16; rg++) {
                int row = nq * 64 + nb * 32 + (rg & 3) + 8 * (rg >> 2) + 4 * hi;
                float v = acc2[nb][rg] + bs;
                v = v > 0.f ? v : 0.f;
                size_t gi = ((size_t)b * NN + row) * DD + col;
                if (TI == 0) out_bf16[gi] = f2b(v);
                else         out_f32[gi] = v;
            }
        }
    }
}

extern "C" void kernel_launch(void* const* d_in, const int* in_sizes, int n_in,
                              void* d_out, int out_size, void* d_ws, size_t ws_size,
                              hipStream_t stream) {
    const float* node   = (const float*)d_in[0];
    const float* W_nw   = (const float*)d_in[1];
    const float* b_nw   = (const float*)d_in[2];
    const float* W_self = (const float*)d_in[3];
    const float* b_self = (const float*)d_in[4];
    const float* W_edge = (const float*)d_in[5];
    const int*   mask   = (const int*)d_in[6];
    const int*   adj    = (const int*)d_in[7];
    float* out = (float*)d_out;
    float* out_w = out + (size_t)BB * NN * DD;   // all_weight region [B][2][N]

    char* ws = (char*)d_ws;
    size_t off = 0;
    unsigned short* Wf    = (unsigned short*)(ws + off); off += (size_t)11 * DD * DD * 2;      // 5.77 MB
    unsigned short* wTf   = (unsigned short*)(ws + off); off += (size_t)BB * DD * NN * 2;      // 16.78 MB
    unsigned short* xb0   = (unsigned short*)(ws + off); off += (size_t)BB * NN * DD * 2;      // 16.78 MB
    unsigned short* xb1   = (unsigned short*)(ws + off); off += (size_t)BB * NN * DD * 2;      // 16.78 MB
    unsigned*       packed= (unsigned*)(ws + off);       off += (size_t)EE * BB * NN * 8 * 4;  // 5.24 MB
    float*          recip = (float*)(ws + off);          off += (size_t)BB * NN * 4;

    k_wconv<<<dim3(1408), dim3(256), 0, stream>>>(W_edge, W_self, Wf);
    k_graph<<<dim3(16384), dim3(256), 0, stream>>>(adj, mask, packed, recip);

    // iteration 0
    k_gt<0><<<dim3(1024), dim3(256), 0, stream>>>(node, nullptr, W_nw, b_nw, out_w, wTf, xb0);
    k2_heavy<0><<<dim3(512), dim3(512), 0, stream>>>(wTf, xb0, Wf, packed, recip, b_self, xb1, nullptr);

    // iteration 1
    k_gt<1><<<dim3(1024), dim3(256), 0, stream>>>(nullptr, xb1, W_nw, b_nw, out_w, wTf, nullptr);
    k2_heavy<1><<<dim3(512), dim3(512), 0, stream>>>(wTf, xb1, Wf, packed, recip, b_self, nullptr, out);
}

// Round 7
// 721.636 us; speedup vs baseline: 4.2887x; 1.0669x over previous
//
#include <hip/hip_runtime.h>
#include <hip/hip_bf16.h>

#define BB 64
#define NN 256
#define DD 512
#define EE 10

typedef __bf16 bf16x8 __attribute__((ext_vector_type(8)));
typedef unsigned short ushort8v __attribute__((ext_vector_type(8)));
typedef unsigned int uint4v __attribute__((ext_vector_type(4)));
typedef unsigned int uint2v __attribute__((ext_vector_type(2)));
typedef float floatx4 __attribute__((ext_vector_type(4)));
typedef float floatx16 __attribute__((ext_vector_type(16)));

typedef __attribute__((address_space(3))) unsigned short lds_us;
typedef const __attribute__((address_space(1))) unsigned short glb_us;

__device__ __forceinline__ unsigned short f2b(float f) {
    union { float f; unsigned u; } x; x.f = f;
    unsigned r = x.u + 0x7FFFu + ((x.u >> 16) & 1u);
    return (unsigned short)(r >> 16);
}
__device__ __forceinline__ float b2f(unsigned short u) {
    union { unsigned u; float f; } x; x.u = ((unsigned)u) << 16;
    return x.f;
}
// pack two rounded bf16 (hi=a, lo=b) from f32 bit patterns via byte-perm
__device__ __forceinline__ unsigned pack_bf16(float a, float b) {
    union { float f; unsigned u; } xa, xb2; xa.f = a; xb2.f = b;
    return __builtin_amdgcn_perm(xa.u + 0x8000u, xb2.u + 0x8000u, 0x07060302u);
}
// v8: build bf16x8 {0,1.0} fragment from two nibble-expanded byte masks
// (n0,n1 hold 0x01/0x00 bytes for bits 0..3 / 4..7). 8 VALU total:
// r80 = 0x80-bytes, r3f = 0x3F-bytes, then v_perm assembles [3F,80] pairs.
__device__ __forceinline__ bf16x8 frag_from_nibs(unsigned n0, unsigned n1) {
    unsigned r80a = n0 << 7, r80b = n1 << 7;
    unsigned r3fa = n0 * 63u, r3fb = n1 * 63u;   // 63 = inline const
    uint4v av;
    av[0] = __builtin_amdgcn_perm(r3fa, r80a, 0x05010400u);  // elems 0,1
    av[1] = __builtin_amdgcn_perm(r3fa, r80a, 0x07030602u);  // elems 2,3
    av[2] = __builtin_amdgcn_perm(r3fb, r80b, 0x05010400u);  // elems 4,5
    av[3] = __builtin_amdgcn_perm(r3fb, r80b, 0x07030602u);  // elems 6,7
    return __builtin_bit_cast(bf16x8, av);
}

// ---------------- K0a: W_edge/W_self -> Wf in 32x32x16 MFMA-B fragment order.
__global__ void k_wconv(const float* __restrict__ W_edge,
                        const float* __restrict__ W_self,
                        unsigned short* __restrict__ Wf) {
    int t = blockIdx.x * 256 + threadIdx.x;   // grid 1408 -> 360448 exact
    int lane  = t & 63;
    int kstep = (t >> 6) & 31;
    int cfg   = (t >> 11) & 15;
    int e     = t >> 15;                      // 0..10
    int dout = cfg * 32 + (lane & 31);
    int k    = kstep * 16 + (lane >> 5) * 8;
    const float* src = (e < EE) ? (W_edge + ((size_t)e * DD + dout) * DD + k)
                                : (W_self + (size_t)dout * DD + k);
    ushort8v o;
    #pragma unroll
    for (int j = 0; j < 8; j++) o[j] = f2b(src[j]);
    *(ushort8v*)(Wf + (size_t)t * 8) = o;
}

// ---------------- K0b: pack graph bits + recip(neigh). One block per (b,n).
__global__ void k_graph(const int* __restrict__ adj, const int* __restrict__ mask,
                        unsigned* __restrict__ packed, float* __restrict__ recip) {
    int b = blockIdx.x >> 8;
    int n = blockIdx.x & 255;
    int lane = threadIdx.x & 63;
    int wv   = threadIdx.x >> 6;   // 0..3
    int m = wv * 64 + lane;
    int ok = (mask[b * NN + n] != 0) & (mask[b * NN + m] != 0) & (m != n);
    __shared__ int cnt_s[4];
    int total = 0;
    #pragma unroll
    for (int e = 0; e < EE; e++) {
        int a = adj[(((size_t)e * BB + b) * NN + n) * NN + m];
        int bit = ok & (a != 0);
        unsigned long long bal = __ballot(bit);
        if (lane == 0) {
            unsigned* dst = packed + (((size_t)e * BB + b) * NN + n) * 8 + wv * 2;
            dst[0] = (unsigned)bal;
            dst[1] = (unsigned)(bal >> 32);
        }
        total += bit;
    }
    for (int off = 32; off; off >>= 1) total += __shfl_down(total, off);
    if (lane == 0) cnt_s[wv] = total;
    __syncthreads();
    if (threadIdx.x == 0) {
        int c = cnt_s[0] + cnt_s[1] + cnt_s[2] + cnt_s[3];
        recip[b * NN + n] = 1.0f / (float)(c < 1 ? 1 : c);
    }
}

// ---------------- K1 fused: gate + bf16 copy + frag-order wTf build.
// Grid 1024 = (b, ms): block handles 16 rows (n = ms*16..+16) x 512 d.
template<int TI>
__global__ __launch_bounds__(256)
void k_gt(const float* __restrict__ xf, const unsigned short* __restrict__ xbin,
          const float* __restrict__ W_nw, const float* __restrict__ b_nw,
          float* __restrict__ w_out, unsigned short* __restrict__ wTf,
          unsigned short* __restrict__ xb0) {
    int bid = blockIdx.x;
    int b  = bid >> 4;
    int ms = bid & 15;
    __shared__ float part[16][17];
    __shared__ float wsig[16];
    int t = threadIdx.x;
    int row = t >> 4;          // 0..15 local n
    int seg = t & 15;          // 32-d segment
    size_t g = ((size_t)(b * NN + ms * 16 + row)) * DD + seg * 32;
    float s = 0.f;
    if (TI == 0) {
        const floatx4* xp = (const floatx4*)(xf + g);
        const floatx4* wp = (const floatx4*)(W_nw + seg * 32);
        #pragma unroll
        for (int k = 0; k < 4; k++) {
            floatx4 a = xp[2 * k], c4 = xp[2 * k + 1];
            floatx4 wa = wp[2 * k], wc = wp[2 * k + 1];
            ushort8v u;
            #pragma unroll
            for (int j = 0; j < 4; j++) {
                s += a[j] * wa[j] + c4[j] * wc[j];
                u[j] = f2b(a[j]); u[4 + j] = f2b(c4[j]);
            }
            *(ushort8v*)(xb0 + g + k * 8) = u;
        }
    } else {
        const ushort8v* xp = (const ushort8v*)(xbin + g);
        const float* wp = W_nw + seg * 32;
        #pragma unroll
        for (int k = 0; k < 4; k++) {
            ushort8v u = xp[k];
            #pragma unroll
            for (int j = 0; j < 8; j++) s += b2f(u[j]) * wp[k * 8 + j];
        }
    }
    part[row][seg] = s;
    __syncthreads();
    if (t < 16) {
        float tot = 0.f;
        #pragma unroll
        for (int i = 0; i < 16; i++) tot += part[t][i];
        float v = 1.f / (1.f + __expf(-(tot + b_nw[0])));
        wsig[t] = v;
        w_out[(b * 2 + TI) * NN + ms * 16 + t] = v;
    }
    __syncthreads();
    // phase 2: write wTf frag-order (elem j = x[m=ms*16+hi*8+j][dd*32+l31] * w[m])
    #pragma unroll
    for (int c = 0; c < 4; c++) {
        int slot = t + 256 * c;          // 0..1023
        int dd_  = slot >> 6;            // 0..15
        int lane = slot & 63;
        int l31 = lane & 31, hi = lane >> 5;
        size_t xrow = ((size_t)(b * NN + ms * 16 + hi * 8)) * DD + dd_ * 32 + l31;
        ushort8v o;
        #pragma unroll
        for (int j = 0; j < 8; j++) {
            float xv = (TI == 0) ? xf[xrow + (size_t)j * DD] : b2f(xbin[xrow + (size_t)j * DD]);
            o[j] = f2b(xv * wsig[hi * 8 + j]);
        }
        *(ushort8v*)(wTf + ((((size_t)b * 16 + ms) * 16 + dd_) * 64 + lane) * 8) = o;
    }
}

// ---------------- K2 v8: v7 chassis (replay-proven: 2-barrier step, per-step
// sWT staging, sTf single-buf handoff, 64n x 256dout, grid 512 = 2 blk/CU)
// with the VALU diet:
//   * per-e nibble cache bq[32] (0x01-bytes, refreshed every 4 steps) +
//     frag_from_nibs: 8 VALU/fragment vs expand_byte's ~20. No aliasing.
//   * single acc3 chain (16 serial MFMA): -16 merge adds, -16 inits, -16 VGPR.
//   * 1/neigh deferred out of stage-1 (linear, per-row): applied once to acc2
//     at the edge->self transition; reference also divides once after e-sum.
// VGPR est ~106 <= 128, no spill.
template<int TI>
__global__ __launch_bounds__(512, 4)
void k2_heavy(const unsigned short* __restrict__ wTf,   // [b][ms16][dd16][lane][8] frag order
              const unsigned short* __restrict__ xb,    // [B][N][D] bf16 (self A)
              const unsigned short* __restrict__ Wf,    // 32x32 frag order [11][cf16][ks32][lane][8]
              const unsigned* __restrict__ packed,      // [E][B][N][8]
              const float* __restrict__ recip,          // [B][N]
              const float* __restrict__ b_self,         // [D]
              unsigned short* __restrict__ out_bf16,    // t=0
              float* __restrict__ out_f32) {            // t=1
    __shared__ __attribute__((aligned(16))) unsigned short sWT[64 * 512]; // 64 KB
    __shared__ __attribute__((aligned(16))) unsigned short sTf[16 * 512]; // 16 KB

    int bid = blockIdx.x;
    int ct = bid & 1;                  // 256-dout half
    int b  = (bid >> 1) & 63;
    int nq = bid >> 7;                 // 64-row n quarter
    int w = threadIdx.x >> 6, lane = threadIdx.x & 63;
    int l31 = lane & 31, hi = lane >> 5;

    // stage-1 role (all waves): s1_d = 32d chunk of 128, s1_nb = 32n half
    int s1_d = w >> 1, s1_nb = w & 1;
    int gn1 = nq * 64 + s1_nb * 32 + l31;         // global n (stage-1 C col)
    // stage-2 role (all waves): w = 32-dout column within ct-half

    floatx16 acc2[2];                             // [nb 32n-half]
    #pragma unroll
    for (int i = 0; i < 2; i++)
        #pragma unroll
        for (int q = 0; q < 16; q++) acc2[i][q] = 0.f;

    auto stage_sWT = [&](int dc2) {               // 64 chunks, 8 per wave
        #pragma unroll
        for (int it = 0; it < 8; it++) {
            int c = it * 8 + w;                   // 0..63: ms = c>>2, dl = c&3
            const unsigned short* g = wTf +
                ((((size_t)b * 16 + (c >> 2)) * 16 + dc2 * 4 + (c & 3)) * 64 + lane) * 8;
            __builtin_amdgcn_global_load_lds((glb_us*)g, (lds_us*)&sWT[c * 512], 16, 0, 0);
        }
    };

    stage_sWT(0);   // prime step 0

    const unsigned short* WfL = Wf + lane * 8;
    const unsigned short* xbL = xb + ((size_t)(b * NN + nq * 64 + l31)) * DD + hi * 8;

    unsigned bq[32];  // per-e nibble-expanded graph masks (0x01-bytes)
                      // [ks*4 + {0,1}] = byte A (m-chunk 2ks) nibbles lo/hi
                      // [ks*4 + {2,3}] = byte B (m-chunk 2ks+1) nibbles lo/hi

    #pragma unroll 1
    for (int s = 0; s < 40; s++) {
        int e = s >> 2, dc2 = s & 3;
        // ---- top sync: sWT chunk for this step has landed ----
        asm volatile("s_waitcnt vmcnt(0) lgkmcnt(0)" ::: "memory");
        __builtin_amdgcn_s_barrier();
        if ((s & 3) == 0) {
            // refresh bq once per e (bits -> 0x01-bytes via nibble-spread mul)
            const uint4v* pp = (const uint4v*)(packed +
                (((size_t)e * BB + b) * NN + gn1) * 8);
            uint4v pa = pp[0], pbv = pp[1];
            unsigned pwv[8] = {pa[0], pa[1], pa[2], pa[3], pbv[0], pbv[1], pbv[2], pbv[3]};
            #pragma unroll
            for (int ks = 0; ks < 8; ks++) {
                unsigned byA = (pwv[ks] >> (hi * 8)) & 0xFFu;
                unsigned byB = (pwv[ks] >> ((2 + hi) * 8)) & 0xFFu;
                bq[ks * 4 + 0] = ((byA & 0xFu) * 0x00204081u) & 0x01010101u;
                bq[ks * 4 + 1] = (((byA >> 4) & 0xFu) * 0x00204081u) & 0x01010101u;
                bq[ks * 4 + 2] = ((byB & 0xFu) * 0x00204081u) & 0x01010101u;
                bq[ks * 4 + 3] = (((byB >> 4) & 0xFu) * 0x00204081u) & 0x01010101u;
            }
        }
        // ---- stage 1 (all waves): 32d x 32n frag of S^T (128d x 64n), K=256 --
        {
            floatx16 acc3;   // single chain (latency hidden at 4 waves/SIMD)
            #pragma unroll
            for (int q = 0; q < 16; q++) acc3[q] = 0.f;
            #pragma unroll
            for (int mk = 0; mk < 16; mk++) {
                bf16x8 afr = __builtin_bit_cast(bf16x8,
                    *(const ushort8v*)&sWT[(mk * 4 + s1_d) * 512 + lane * 8]);
                bf16x8 bg = frag_from_nibs(bq[(mk >> 1) * 4 + (mk & 1) * 2],
                                           bq[(mk >> 1) * 4 + (mk & 1) * 2 + 1]);
                acc3 = __builtin_amdgcn_mfma_f32_32x32x16_bf16(afr, bg, acc3, 0, 0, 0);
            }
            // pack (NO rn scale - deferred), write frag-order sTf
            #pragma unroll
            for (int g = 0; g < 4; g++) {
                uint2v pk;
                pk[0] = pack_bf16(acc3[g * 4 + 1], acc3[g * 4 + 0]);
                pk[1] = pack_bf16(acc3[g * 4 + 3], acc3[g * 4 + 2]);
                int kk_w = s1_d * 2 + (g >> 1);           // 16-d chunk of 128
                int slot = (kk_w * 2 + s1_nb) * 64 + (g & 1) * 32 + l31;
                *(uint2v*)&sTf[slot * 8 + 4 * hi] = pk;
            }
        }
        // ---- mid sync: sTf visible; sWT dead ----
        asm volatile("s_waitcnt lgkmcnt(0)" ::: "memory");
        __builtin_amdgcn_s_barrier();
        if (s + 1 < 40) stage_sWT((s + 1) & 3);
        // ---- stage 2 (all waves): acc2 += S(64n x 128d) @ Wf col (32 dout) --
        #pragma unroll
        for (int kk = 0; kk < 8; kk++) {
            bf16x8 bfr = __builtin_bit_cast(bf16x8, *(const ushort8v*)
                &WfL[(size_t)(((e * 16 + ct * 8 + w) * 32 + dc2 * 8 + kk)) * 512]);
            bf16x8 afr0 = __builtin_bit_cast(bf16x8,
                *(const ushort8v*)&sTf[((kk * 2 + 0) * 64 + lane) * 8]);
            bf16x8 afr1 = __builtin_bit_cast(bf16x8,
                *(const ushort8v*)&sTf[((kk * 2 + 1) * 64 + lane) * 8]);
            acc2[0] = __builtin_amdgcn_mfma_f32_32x32x16_bf16(afr0, bfr, acc2[0], 0, 0, 0);
            acc2[1] = __builtin_amdgcn_mfma_f32_32x32x16_bf16(afr1, bfr, acc2[1], 0, 0, 0);
        }
    }
    // ---- transition: apply deferred 1/neigh to the edge aggregate ----
    #pragma unroll
    for (int nb = 0; nb < 2; nb++) {
        #pragma unroll
        for (int rg = 0; rg < 16; rg++) {
            int row = nq * 64 + nb * 32 + (rg & 3) + 8 * (rg >> 2) + 4 * hi;
            acc2[nb][rg] *= recip[b * NN + row];
        }
    }
    // ---- self path: A direct from xb, barrier-free tail (unscaled) ----
    #pragma unroll 1
    for (int dc2 = 0; dc2 < 4; dc2++) {
        #pragma unroll
        for (int kk = 0; kk < 8; kk++) {
            bf16x8 bfr = __builtin_bit_cast(bf16x8, *(const ushort8v*)
                &WfL[(size_t)(((EE * 16 + ct * 8 + w) * 32 + dc2 * 8 + kk)) * 512]);
            bf16x8 afr0 = __builtin_bit_cast(bf16x8, *(const ushort8v*)
                &xbL[(size_t)0 * 32 * DD + (dc2 * 8 + kk) * 16]);
            bf16x8 afr1 = __builtin_bit_cast(bf16x8, *(const ushort8v*)
                &xbL[(size_t)1 * 32 * DD + (dc2 * 8 + kk) * 16]);
            acc2[0] = __builtin_amdgcn_mfma_f32_32x32x16_bf16(afr0, bfr, acc2[0], 0, 0, 0);
            acc2[1] = __builtin_amdgcn_mfma_f32_32x32x16_bf16(afr1, bfr, acc2[1], 0, 0, 0);
        }
    }
    // ---- epilogue: +b_self, relu, store (C rows=n, cols=dout) ----
    {
        int col = ct * 256 + w * 32 + l31;
        float bs = b_self[col];
        #pragma unroll
        for (int nb = 0; nb < 2; nb++) {
            #pragma unroll
            for (int rg = 0; rg < 16; rg++) {
                int row = nq * 64 + nb * 32 + (rg & 3) + 8 * (rg >> 2) + 4 * hi;
                float v = acc2[nb][rg] + bs;
                v = v > 0.f ? v : 0.f;
                size_t gi = ((size_t)b * NN + row) * DD + col;
                if (TI == 0) out_bf16[gi] = f2b(v);
                else         out_f32[gi] = v;
            }
        }
    }
}

extern "C" void kernel_launch(void* const* d_in, const int* in_sizes, int n_in,
                              void* d_out, int out_size, void* d_ws, size_t ws_size,
                              hipStream_t stream) {
    const float* node   = (const float*)d_in[0];
    const float* W_nw   = (const float*)d_in[1];
    const float* b_nw   = (const float*)d_in[2];
    const float* W_self = (const float*)d_in[3];
    const float* b_self = (const float*)d_in[4];
    const float* W_edge = (const float*)d_in[5];
    const int*   mask   = (const int*)d_in[6];
    const int*   adj    = (const int*)d_in[7];
    float* out = (float*)d_out;
    float* out_w = out + (size_t)BB * NN * DD;   // all_weight region [B][2][N]

    char* ws = (char*)d_ws;
    size_t off = 0;
    unsigned short* Wf    = (unsigned short*)(ws + off); off += (size_t)11 * DD * DD * 2;      // 5.77 MB
    unsigned short* wTf   = (unsigned short*)(ws + off); off += (size_t)BB * DD * NN * 2;      // 16.78 MB
    unsigned short* xb0   = (unsigned short*)(ws + off); off += (size_t)BB * NN * DD * 2;      // 16.78 MB
    unsigned short* xb1   = (unsigned short*)(ws + off); off += (size_t)BB * NN * DD * 2;      // 16.78 MB
    unsigned*       packed= (unsigned*)(ws + off);       off += (size_t)EE * BB * NN * 8 * 4;  // 5.24 MB
    float*          recip = (float*)(ws + off);          off += (size_t)BB * NN * 4;

    k_wconv<<<dim3(1408), dim3(256), 0, stream>>>(W_edge, W_self, Wf);
    k_graph<<<dim3(16384), dim3(256), 0, stream>>>(adj, mask, packed, recip);

    // iteration 0
    k_gt<0><<<dim3(1024), dim3(256), 0, stream>>>(node, nullptr, W_nw, b_nw, out_w, wTf, xb0);
    k2_heavy<0><<<dim3(512), dim3(512), 0, stream>>>(wTf, xb0, Wf, packed, recip, b_self, xb1, nullptr);

    // iteration 1
    k_gt<1><<<dim3(1024), dim3(256), 0, stream>>>(nullptr, xb1, W_nw, b_nw, out_w, wTf, nullptr);
    k2_heavy<1><<<dim3(512), dim3(512), 0, stream>>>(wTf, xb1, Wf, packed, recip, b_self, nullptr, out);
}